// Round 2
// baseline (476.804 us; speedup 1.0000x reference)
//
#include <hip/hip_runtime.h>
#include <stdint.h>

typedef unsigned short u16;
typedef float v4f __attribute__((ext_vector_type(4)));
typedef short v8s __attribute__((ext_vector_type(8)));

#define B_   8192
#define IN_  1024
#define OUT_ 1024
#define D_   8

#define BM 128
#define BN 128
#define BK 32
#define SPLITD 2          // blockIdx.z splits the d-loop: 2 halves of 4 epochs

__device__ __forceinline__ u16 f2bf(float f) {
  uint32_t u = __float_as_uint(f);
  u += 0x7fffu + ((u >> 16) & 1u);   // round-to-nearest-even (inputs are finite)
  return (u16)(u >> 16);
}

// Convert input (8M fp32) and weights (8M fp32) to bf16 in workspace.
__global__ __launch_bounds__(256) void convert_kernel(
    const float* __restrict__ input, const float* __restrict__ weights,
    u16* __restrict__ inBf, u16* __restrict__ wtBf) {
  int i4 = blockIdx.x * blockDim.x + threadIdx.x;   // one float4 per thread
  const int n4 = (B_ * IN_) / 4;
  const float* src;
  u16* dst;
  int idx;
  if (i4 < n4) { src = input;   dst = inBf; idx = i4; }
  else         { src = weights; dst = wtBf; idx = i4 - n4; }
  float4 v = ((const float4*)src)[idx];
  ushort4 o;
  o.x = f2bf(v.x); o.y = f2bf(v.y); o.z = f2bf(v.z); o.w = f2bf(v.w);
  ((ushort4*)dst)[idx] = o;
}

// out[b,o] = sum_d w[b,d]*biases[d,o]  (the bias term; also serves as the
// zero-init for the GEMM's atomicAdd accumulation). Write-bound: 32 MB.
__global__ __launch_bounds__(256) void bias_init(
    const float* __restrict__ w, const float* __restrict__ biases,
    float* __restrict__ out) {
  int idx = blockIdx.x * 256 + threadIdx.x;   // one float4 of out
  int b  = idx >> 8;                          // OUT_/4 = 256 float4 per row
  int o4 = (idx & 255) << 2;
  const float* wr_ = w + (size_t)b * D_;
  v4f acc = {0.f, 0.f, 0.f, 0.f};
#pragma unroll
  for (int d = 0; d < D_; ++d) {
    v4f bv = *(const v4f*)(biases + d * OUT_ + o4);
    acc += wr_[d] * bv;
  }
  *(v4f*)(out + (size_t)b * OUT_ + o4) = acc;
}

__device__ __forceinline__ void gload_lds16(const u16* g, u16* l) {
  typedef __attribute__((address_space(1))) void gvoid;
  typedef __attribute__((address_space(3))) void lvoid;
  __builtin_amdgcn_global_load_lds((gvoid*)g, (lvoid*)l, 16, 0, 0);
}

// GEMM: atomicAdd into out of sum_{d in half} w[b,d] * (input[b,:] . weights[d,o,:])
// m97 structure: 128x128 tile, BK=32, 4 waves each computing a 64x64 quadrant via
// 4x4 tiles of mfma_f32_16x16x32_bf16. Per-d-epoch accumulator folded by w[b,d].
// blockIdx.z selects the d-half (split-K for occupancy: 1024 blocks = ~3-4/CU).
__global__ __launch_bounds__(256) void gemm_dyn(
    const u16* __restrict__ A,        // [B_][IN_] bf16 (unscaled input)
    const u16* __restrict__ Wt,       // [D_][OUT_][IN_] bf16
    const float* __restrict__ w,      // [B_][D_]
    float* __restrict__ out) {        // [B_][OUT_] (pre-initialized with bias term)
  __shared__ __align__(16) u16 As[BM * BK];   // [m][k] row-major, 8 KB
  __shared__ __align__(16) u16 Bs[BN * BK];   // [n][k] row-major, 8 KB

  const int tid  = threadIdx.x;
  const int wid  = tid >> 6;
  const int lane = tid & 63;
  const int wr   = wid >> 1, wc = wid & 1;    // wave quadrant in 128x128
  const int quad = lane >> 4, l16 = lane & 15;
  const int m0   = blockIdx.y * BM;
  const int n0   = blockIdx.x * BN;
  const int d0   = blockIdx.z * (D_ / SPLITD);

  // ---- staging: 512 chunks of 16B per 8KB tile; 2 chunks/thread, wave-contiguous
  const int c0  = wid * 128 + lane;
  const int c1  = c0 + 64;
  const int rA0 = c0 >> 2, cA0 = (c0 & 3) << 3;
  const int rA1 = c1 >> 2, cA1 = (c1 & 3) << 3;
  const u16* aP0 = A + (size_t)(m0 + rA0) * IN_ + cA0;
  const u16* aP1 = A + (size_t)(m0 + rA1) * IN_ + cA1;
  const u16* bB0 = Wt + (size_t)(n0 + rA0) * IN_ + cA0;
  const u16* bB1 = Wt + (size_t)(n0 + rA1) * IN_ + cA1;
  u16* lA0 = As + c0 * 8;
  u16* lA1 = As + c1 * 8;
  u16* lB0 = Bs + c0 * 8;
  u16* lB1 = Bs + c1 * 8;

  // ---- fragment LDS offsets (u16 index); mt/nt adds 16*BK
  const int aOff = (wr * 64 + l16) * BK + quad * 8;
  const int bOff = (wc * 64 + l16) * BK + quad * 8;

  const v4f vzero = {0.f, 0.f, 0.f, 0.f};
  v4f fin[4][4];
#pragma unroll
  for (int mt = 0; mt < 4; ++mt)
#pragma unroll
    for (int nt = 0; nt < 4; ++nt) fin[mt][nt] = vzero;

  for (int dd = 0; dd < D_ / SPLITD; ++dd) {
    const int d = d0 + dd;
    const u16* bP0 = bB0 + (size_t)d * OUT_ * IN_;
    const u16* bP1 = bB1 + (size_t)d * OUT_ * IN_;
    v4f acc[4][4];
#pragma unroll
    for (int mt = 0; mt < 4; ++mt)
#pragma unroll
      for (int nt = 0; nt < 4; ++nt) acc[mt][nt] = vzero;

    for (int it = 0; it < 32; ++it) {
      const int i0 = it * BK;
      gload_lds16(aP0 + i0, lA0);
      gload_lds16(aP1 + i0, lA1);
      gload_lds16(bP0 + i0, lB0);
      gload_lds16(bP1 + i0, lB1);
      __builtin_amdgcn_s_waitcnt(0);
      __syncthreads();

      v8s af[4], bf[4];
#pragma unroll
      for (int mt = 0; mt < 4; ++mt)
        af[mt] = *(const v8s*)(As + aOff + mt * 16 * BK);
#pragma unroll
      for (int nt = 0; nt < 4; ++nt)
        bf[nt] = *(const v8s*)(Bs + bOff + nt * 16 * BK);
#pragma unroll
      for (int mt = 0; mt < 4; ++mt)
#pragma unroll
        for (int nt = 0; nt < 4; ++nt)
          acc[mt][nt] = __builtin_amdgcn_mfma_f32_16x16x32_bf16(
              af[mt], bf[nt], acc[mt][nt], 0, 0, 0);
      __syncthreads();
    }

    // fold this d-epoch into fin with per-row scale w[row, d]
#pragma unroll
    for (int mt = 0; mt < 4; ++mt) {
      const int rowb = m0 + wr * 64 + mt * 16 + quad * 4;
#pragma unroll
      for (int r = 0; r < 4; ++r) {
        const float ws_ = w[(size_t)(rowb + r) * D_ + d];
#pragma unroll
        for (int nt = 0; nt < 4; ++nt) fin[mt][nt][r] += ws_ * acc[mt][nt][r];
      }
    }
  }

  // ---- epilogue: atomic-accumulate partial into out (bias term pre-written)
#pragma unroll
  for (int mt = 0; mt < 4; ++mt) {
#pragma unroll
    for (int r = 0; r < 4; ++r) {
      const int grow = m0 + wr * 64 + mt * 16 + quad * 4 + r;
#pragma unroll
      for (int nt = 0; nt < 4; ++nt) {
        const int col = n0 + wc * 64 + nt * 16 + l16;
        atomicAdd(&out[(size_t)grow * OUT_ + col], fin[mt][nt][r]);
      }
    }
  }
}

extern "C" void kernel_launch(void* const* d_in, const int* in_sizes, int n_in,
                              void* d_out, int out_size, void* d_ws, size_t ws_size,
                              hipStream_t stream) {
  const float* input   = (const float*)d_in[0];
  const float* w       = (const float*)d_in[1];
  const float* weights = (const float*)d_in[2];
  const float* biases  = (const float*)d_in[3];
  float* out = (float*)d_out;

  u16* inBf = (u16*)d_ws;                       // 16 MB
  u16* wtBf = inBf + (size_t)B_ * IN_;          // 16 MB

  const int totalF4 = (B_ * IN_ + D_ * OUT_ * IN_) / 4;   // 4M
  convert_kernel<<<dim3(totalF4 / 256), 256, 0, stream>>>(input, weights, inBf, wtBf);
  bias_init<<<dim3(B_ * OUT_ / 4 / 256), 256, 0, stream>>>(w, biases, out);
  gemm_dyn<<<dim3(OUT_ / BN, B_ / BM, SPLITD), 256, 0, stream>>>(inBf, wtBf, w, out);
}

// Round 3
// 378.924 us; speedup vs baseline: 1.2583x; 1.2583x over previous
//
#include <hip/hip_runtime.h>
#include <stdint.h>

typedef unsigned short u16;
typedef float v4f __attribute__((ext_vector_type(4)));
typedef short v8s __attribute__((ext_vector_type(8)));

#define B_   8192
#define IN_  1024
#define OUT_ 1024
#define D_   8

#define BM 128
#define BN 128
#define BK 32
#define SPLITD 2          // blockIdx.z splits the d-range: 2 halves of 4 epochs
#define KROW (D_ * IN_)   // 8192: row length of the scaled-A matrix

__device__ __forceinline__ u16 f2bf(float f) {
  uint32_t u = __float_as_uint(f);
  u += 0x7fffu + ((u >> 16) & 1u);   // round-to-nearest-even (inputs are finite)
  return (u16)(u >> 16);
}

// ---- main path converts -----------------------------------------------------
// A'[b][d*IN+i] = bf16(w[b,d] * input[b,i]).  One block per input row b.
__global__ __launch_bounds__(256) void convert_a_scaled(
    const float* __restrict__ input, const float* __restrict__ w,
    u16* __restrict__ aS) {
  const int b  = blockIdx.x;            // 8192 blocks
  const int i4 = threadIdx.x;           // 256 float4 per row
  float4 v = ((const float4*)(input + (size_t)b * IN_))[i4];
  const float* wr_ = w + (size_t)b * D_;   // wave-uniform -> scalar loads
  ushort4* dst = (ushort4*)aS + (size_t)b * (KROW / 4);
#pragma unroll
  for (int d = 0; d < D_; ++d) {
    const float s = wr_[d];
    ushort4 o;
    o.x = f2bf(s * v.x); o.y = f2bf(s * v.y);
    o.z = f2bf(s * v.z); o.w = f2bf(s * v.w);
    dst[d * (IN_ / 4) + i4] = o;
  }
}

__global__ __launch_bounds__(256) void convert_w_only(
    const float* __restrict__ weights, u16* __restrict__ wtBf) {
  int idx = blockIdx.x * 256 + threadIdx.x;   // one float4 per thread, 8192 blocks
  float4 v = ((const float4*)weights)[idx];
  ushort4 o;
  o.x = f2bf(v.x); o.y = f2bf(v.y); o.z = f2bf(v.z); o.w = f2bf(v.w);
  ((ushort4*)wtBf)[idx] = o;
}

// out[b,o] = sum_d w[b,d]*biases[d,o]  (bias term + zero-init for atomics)
__global__ __launch_bounds__(256) void bias_init(
    const float* __restrict__ w, const float* __restrict__ biases,
    float* __restrict__ out) {
  int idx = blockIdx.x * 256 + threadIdx.x;
  int b  = idx >> 8;
  int o4 = (idx & 255) << 2;
  const float* wr_ = w + (size_t)b * D_;
  v4f acc = {0.f, 0.f, 0.f, 0.f};
#pragma unroll
  for (int d = 0; d < D_; ++d) {
    v4f bv = *(const v4f*)(biases + d * OUT_ + o4);
    acc += wr_[d] * bv;
  }
  *(v4f*)(out + (size_t)b * OUT_ + o4) = acc;
}

__device__ __forceinline__ void gload_lds16(const u16* g, u16* l) {
  typedef __attribute__((address_space(1))) void gvoid;
  typedef __attribute__((address_space(3))) void lvoid;
  __builtin_amdgcn_global_load_lds((gvoid*)g, (lvoid*)l, 16, 0, 0);
}

// ---- main GEMM: pure m97 structure, single accumulator ---------------------
// atomicAdd partials of A'[.,k-half] x Wt[.,k-half]^T into pre-biased out.
__global__ __launch_bounds__(256) void gemm_main(
    const u16* __restrict__ A,        // [B_][KROW] bf16, pre-scaled by w
    const u16* __restrict__ Wt,       // [D_][OUT_][IN_] bf16
    float* __restrict__ out) {        // [B_][OUT_] (pre-initialized with bias)
  __shared__ __align__(16) u16 As[BM * BK];   // 8 KB
  __shared__ __align__(16) u16 Bs[BN * BK];   // 8 KB

  const int tid  = threadIdx.x;
  const int wid  = tid >> 6;
  const int lane = tid & 63;
  const int wr   = wid >> 1, wc = wid & 1;
  const int quad = lane >> 4, l16 = lane & 15;
  const int m0   = blockIdx.y * BM;
  const int n0   = blockIdx.x * BN;
  const int d0   = blockIdx.z * (D_ / SPLITD);

  const int c0  = wid * 128 + lane;
  const int c1  = c0 + 64;
  const int rA0 = c0 >> 2, cA0 = (c0 & 3) << 3;
  const int rA1 = c1 >> 2, cA1 = (c1 & 3) << 3;
  // A base: row (m0+r), k-offset d0*IN_ + chunk col
  const u16* aB0 = A + (size_t)(m0 + rA0) * KROW + d0 * IN_ + cA0;
  const u16* aB1 = A + (size_t)(m0 + rA1) * KROW + d0 * IN_ + cA1;
  // B base: weights[d][n0+r][chunk col]
  const u16* bB0 = Wt + ((size_t)d0 * OUT_ + n0 + rA0) * IN_ + cA0;
  const u16* bB1 = Wt + ((size_t)d0 * OUT_ + n0 + rA1) * IN_ + cA1;
  u16* lA0 = As + c0 * 8;
  u16* lA1 = As + c1 * 8;
  u16* lB0 = Bs + c0 * 8;
  u16* lB1 = Bs + c1 * 8;

  const int aOff = (wr * 64 + l16) * BK + quad * 8;
  const int bOff = (wc * 64 + l16) * BK + quad * 8;

  const v4f vzero = {0.f, 0.f, 0.f, 0.f};
  v4f acc[4][4];
#pragma unroll
  for (int mt = 0; mt < 4; ++mt)
#pragma unroll
    for (int nt = 0; nt < 4; ++nt) acc[mt][nt] = vzero;

  for (int dd = 0; dd < D_ / SPLITD; ++dd) {
    const u16* aP0 = aB0 + dd * IN_;
    const u16* aP1 = aB1 + dd * IN_;
    const u16* bP0 = bB0 + (size_t)dd * OUT_ * IN_;
    const u16* bP1 = bB1 + (size_t)dd * OUT_ * IN_;
    for (int it = 0; it < 32; ++it) {
      const int i0 = it * BK;
      gload_lds16(aP0 + i0, lA0);
      gload_lds16(aP1 + i0, lA1);
      gload_lds16(bP0 + i0, lB0);
      gload_lds16(bP1 + i0, lB1);
      __builtin_amdgcn_s_waitcnt(0);
      __syncthreads();

      v8s af[4], bf[4];
#pragma unroll
      for (int mt = 0; mt < 4; ++mt)
        af[mt] = *(const v8s*)(As + aOff + mt * 16 * BK);
#pragma unroll
      for (int nt = 0; nt < 4; ++nt)
        bf[nt] = *(const v8s*)(Bs + bOff + nt * 16 * BK);
#pragma unroll
      for (int mt = 0; mt < 4; ++mt)
#pragma unroll
        for (int nt = 0; nt < 4; ++nt)
          acc[mt][nt] = __builtin_amdgcn_mfma_f32_16x16x32_bf16(
              af[mt], bf[nt], acc[mt][nt], 0, 0, 0);
      __syncthreads();
    }
  }

#pragma unroll
  for (int mt = 0; mt < 4; ++mt) {
#pragma unroll
    for (int r = 0; r < 4; ++r) {
      const int grow = m0 + wr * 64 + mt * 16 + quad * 4 + r;
#pragma unroll
      for (int nt = 0; nt < 4; ++nt) {
        const int col = n0 + wc * 64 + nt * 16 + l16;
        atomicAdd(&out[(size_t)grow * OUT_ + col], acc[mt][nt][r]);
      }
    }
  }
}

// ---- fallback path (R1, proven): used only if ws is too small --------------
__global__ __launch_bounds__(256) void convert_both(
    const float* __restrict__ input, const float* __restrict__ weights,
    u16* __restrict__ inBf, u16* __restrict__ wtBf) {
  int i4 = blockIdx.x * blockDim.x + threadIdx.x;
  const int n4 = (B_ * IN_) / 4;
  const float* src;
  u16* dst;
  int idx;
  if (i4 < n4) { src = input;   dst = inBf; idx = i4; }
  else         { src = weights; dst = wtBf; idx = i4 - n4; }
  float4 v = ((const float4*)src)[idx];
  ushort4 o;
  o.x = f2bf(v.x); o.y = f2bf(v.y); o.z = f2bf(v.z); o.w = f2bf(v.w);
  ((ushort4*)dst)[idx] = o;
}

__global__ __launch_bounds__(256) void gemm_fallback(
    const u16* __restrict__ A, const u16* __restrict__ Wt,
    const float* __restrict__ w, const float* __restrict__ biases,
    float* __restrict__ out) {
  __shared__ __align__(16) u16 As[BM * BK];
  __shared__ __align__(16) u16 Bs[BN * BK];
  const int tid  = threadIdx.x;
  const int wid  = tid >> 6;
  const int lane = tid & 63;
  const int wr   = wid >> 1, wc = wid & 1;
  const int quad = lane >> 4, l16 = lane & 15;
  const int m0   = blockIdx.y * BM;
  const int n0   = blockIdx.x * BN;
  const int c0  = wid * 128 + lane;
  const int c1  = c0 + 64;
  const int rA0 = c0 >> 2, cA0 = (c0 & 3) << 3;
  const int rA1 = c1 >> 2, cA1 = (c1 & 3) << 3;
  const u16* aP0 = A + (size_t)(m0 + rA0) * IN_ + cA0;
  const u16* aP1 = A + (size_t)(m0 + rA1) * IN_ + cA1;
  const u16* bB0 = Wt + (size_t)(n0 + rA0) * IN_ + cA0;
  const u16* bB1 = Wt + (size_t)(n0 + rA1) * IN_ + cA1;
  u16* lA0 = As + c0 * 8;
  u16* lA1 = As + c1 * 8;
  u16* lB0 = Bs + c0 * 8;
  u16* lB1 = Bs + c1 * 8;
  const int aOff = (wr * 64 + l16) * BK + quad * 8;
  const int bOff = (wc * 64 + l16) * BK + quad * 8;
  const v4f vzero = {0.f, 0.f, 0.f, 0.f};
  v4f fin[4][4];
#pragma unroll
  for (int mt = 0; mt < 4; ++mt)
#pragma unroll
    for (int nt = 0; nt < 4; ++nt) fin[mt][nt] = vzero;
  for (int d = 0; d < D_; ++d) {
    const u16* bP0 = bB0 + (size_t)d * OUT_ * IN_;
    const u16* bP1 = bB1 + (size_t)d * OUT_ * IN_;
    v4f acc[4][4];
#pragma unroll
    for (int mt = 0; mt < 4; ++mt)
#pragma unroll
      for (int nt = 0; nt < 4; ++nt) acc[mt][nt] = vzero;
    for (int it = 0; it < 32; ++it) {
      const int i0 = it * BK;
      gload_lds16(aP0 + i0, lA0);
      gload_lds16(aP1 + i0, lA1);
      gload_lds16(bP0 + i0, lB0);
      gload_lds16(bP1 + i0, lB1);
      __builtin_amdgcn_s_waitcnt(0);
      __syncthreads();
      v8s af[4], bf[4];
#pragma unroll
      for (int mt = 0; mt < 4; ++mt)
        af[mt] = *(const v8s*)(As + aOff + mt * 16 * BK);
#pragma unroll
      for (int nt = 0; nt < 4; ++nt)
        bf[nt] = *(const v8s*)(Bs + bOff + nt * 16 * BK);
#pragma unroll
      for (int mt = 0; mt < 4; ++mt)
#pragma unroll
        for (int nt = 0; nt < 4; ++nt)
          acc[mt][nt] = __builtin_amdgcn_mfma_f32_16x16x32_bf16(
              af[mt], bf[nt], acc[mt][nt], 0, 0, 0);
      __syncthreads();
    }
#pragma unroll
    for (int mt = 0; mt < 4; ++mt) {
      const int rowb = m0 + wr * 64 + mt * 16 + quad * 4;
#pragma unroll
      for (int r = 0; r < 4; ++r) {
        const float ws_ = w[(size_t)(rowb + r) * D_ + d];
#pragma unroll
        for (int nt = 0; nt < 4; ++nt) fin[mt][nt][r] += ws_ * acc[mt][nt][r];
      }
    }
  }
  float bcol[4][8];
#pragma unroll
  for (int nt = 0; nt < 4; ++nt) {
    const int col = n0 + wc * 64 + nt * 16 + l16;
#pragma unroll
    for (int dd = 0; dd < 8; ++dd) bcol[nt][dd] = biases[dd * OUT_ + col];
  }
#pragma unroll
  for (int mt = 0; mt < 4; ++mt) {
#pragma unroll
    for (int r = 0; r < 4; ++r) {
      const int grow = m0 + wr * 64 + mt * 16 + quad * 4 + r;
      const v4f* wp = (const v4f*)(w + (size_t)grow * D_);
      const v4f wa = wp[0], wb = wp[1];
#pragma unroll
      for (int nt = 0; nt < 4; ++nt) {
        const int col = n0 + wc * 64 + nt * 16 + l16;
        const float bias = wa[0] * bcol[nt][0] + wa[1] * bcol[nt][1] +
                           wa[2] * bcol[nt][2] + wa[3] * bcol[nt][3] +
                           wb[0] * bcol[nt][4] + wb[1] * bcol[nt][5] +
                           wb[2] * bcol[nt][6] + wb[3] * bcol[nt][7];
        out[(size_t)grow * OUT_ + col] = fin[mt][nt][r] + bias;
      }
    }
  }
}

extern "C" void kernel_launch(void* const* d_in, const int* in_sizes, int n_in,
                              void* d_out, int out_size, void* d_ws, size_t ws_size,
                              hipStream_t stream) {
  const float* input   = (const float*)d_in[0];
  const float* w       = (const float*)d_in[1];
  const float* weights = (const float*)d_in[2];
  const float* biases  = (const float*)d_in[3];
  float* out = (float*)d_out;

  const size_t aS_bytes = (size_t)B_ * KROW * 2;          // 128 MB
  const size_t wt_bytes = (size_t)D_ * OUT_ * IN_ * 2;    // 16 MB

  if (ws_size >= aS_bytes + wt_bytes) {
    u16* aS   = (u16*)d_ws;
    u16* wtBf = (u16*)((char*)d_ws + aS_bytes);
    convert_a_scaled<<<dim3(B_), 256, 0, stream>>>(input, w, aS);
    convert_w_only<<<dim3(D_ * OUT_ * IN_ / 4 / 256), 256, 0, stream>>>(weights, wtBf);
    bias_init<<<dim3(B_ * OUT_ / 4 / 256), 256, 0, stream>>>(w, biases, out);
    gemm_main<<<dim3(OUT_ / BN, B_ / BM, SPLITD), 256, 0, stream>>>(aS, wtBf, out);
  } else {
    u16* inBf = (u16*)d_ws;
    u16* wtBf = inBf + (size_t)B_ * IN_;
    const int totalF4 = (B_ * IN_ + D_ * OUT_ * IN_) / 4;
    convert_both<<<dim3(totalF4 / 256), 256, 0, stream>>>(input, weights, inBf, wtBf);
    gemm_fallback<<<dim3(OUT_ / BN, B_ / BM), 256, 0, stream>>>(inBf, wtBf, w, biases, out);
  }
}

// Round 4
// 336.946 us; speedup vs baseline: 1.4151x; 1.1246x over previous
//
#include <hip/hip_runtime.h>
#include <stdint.h>

typedef unsigned short u16;
typedef float v4f __attribute__((ext_vector_type(4)));
typedef short v8s __attribute__((ext_vector_type(8)));

#define B_   8192
#define IN_  1024
#define OUT_ 1024
#define D_   8

#define BM 128
#define BN 128
#define BK 32
#define SPLITD 2          // d-range split: 2 halves of 4 epochs (K=4096 each)
#define KROW (D_ * IN_)   // 8192: row length of the scaled-A matrix

__device__ __forceinline__ u16 f2bf(float f) {
  uint32_t u = __float_as_uint(f);
  u += 0x7fffu + ((u >> 16) & 1u);   // round-to-nearest-even (inputs are finite)
  return (u16)(u >> 16);
}

// ---- fused prep: one launch does all three independent pre-GEMM jobs ------
//   blocks [0, 8192):        A'[b][d*IN+i] = bf16(w[b,d] * input[b,i])
//   blocks [8192, 16384):    wtBf = bf16(weights)
//   blocks [16384, 24576):   out[b,o] = sum_d w[b,d]*biases[d,o]  (bias + init)
__global__ __launch_bounds__(256) void prep_fused(
    const float* __restrict__ input, const float* __restrict__ w,
    const float* __restrict__ weights, const float* __restrict__ biases,
    u16* __restrict__ aS, u16* __restrict__ wtBf, float* __restrict__ out) {
  const int bid = blockIdx.x;
  const int tid = threadIdx.x;
  if (bid < 8192) {
    const int b  = bid;
    const int i4 = tid;
    float4 v = ((const float4*)(input + (size_t)b * IN_))[i4];
    const float* wr_ = w + (size_t)b * D_;   // wave-uniform -> scalar loads
    ushort4* dst = (ushort4*)aS + (size_t)b * (KROW / 4);
#pragma unroll
    for (int d = 0; d < D_; ++d) {
      const float s = wr_[d];
      ushort4 o;
      o.x = f2bf(s * v.x); o.y = f2bf(s * v.y);
      o.z = f2bf(s * v.z); o.w = f2bf(s * v.w);
      dst[d * (IN_ / 4) + i4] = o;
    }
  } else if (bid < 16384) {
    int idx = (bid - 8192) * 256 + tid;      // one float4 of weights
    float4 v = ((const float4*)weights)[idx];
    ushort4 o;
    o.x = f2bf(v.x); o.y = f2bf(v.y); o.z = f2bf(v.z); o.w = f2bf(v.w);
    ((ushort4*)wtBf)[idx] = o;
  } else {
    int idx = (bid - 16384) * 256 + tid;     // one float4 of out
    int b  = idx >> 8;
    int o4 = (idx & 255) << 2;
    const float* wr_ = w + (size_t)b * D_;
    v4f acc = {0.f, 0.f, 0.f, 0.f};
#pragma unroll
    for (int d = 0; d < D_; ++d) {
      v4f bv = *(const v4f*)(biases + d * OUT_ + o4);
      acc += wr_[d] * bv;
    }
    *(v4f*)(out + (size_t)b * OUT_ + o4) = acc;
  }
}

__device__ __forceinline__ void gload_lds16(const u16* g, u16* l) {
  typedef __attribute__((address_space(1))) void gvoid;
  typedef __attribute__((address_space(3))) void lvoid;
  __builtin_amdgcn_global_load_lds((gvoid*)g, (lvoid*)l, 16, 0, 0);
}

// ---- main GEMM: m97 structure + XCD-aware swizzle --------------------------
// 1D grid of 1024 blocks. Decode so that blocks sharing an A'-row-slab (same y)
// land on ONE XCD (assuming dispatch round-robins id%8 across the 8 XCDs):
//   xcd = id & 7 ; slot = id >> 3
//   y = xcd + 8 * (slot & 7)      -> XCD k owns y in {k, k+8, ..., k+56}
//   x = (slot >> 3) & 7 ; z = slot >> 6
// Per XCD: A' slabs 16 MB + B 16 MB fetched once into its L2 instead of
// every XCD re-fetching everything (~6x duplicate fill at R3).
__global__ __launch_bounds__(256) void gemm_main(
    const u16* __restrict__ A,        // [B_][KROW] bf16, pre-scaled by w
    const u16* __restrict__ Wt,       // [D_][OUT_][IN_] bf16
    float* __restrict__ out) {        // [B_][OUT_] (pre-initialized with bias)
  __shared__ __align__(16) u16 As[BM * BK];   // 8 KB
  __shared__ __align__(16) u16 Bs[BN * BK];   // 8 KB

  const int id   = blockIdx.x;
  const int xcd  = id & 7;
  const int slot = id >> 3;
  const int by   = xcd + ((slot & 7) << 3);
  const int bx   = (slot >> 3) & 7;
  const int bz   = slot >> 6;

  const int tid  = threadIdx.x;
  const int wid  = tid >> 6;
  const int lane = tid & 63;
  const int wr   = wid >> 1, wc = wid & 1;
  const int quad = lane >> 4, l16 = lane & 15;
  const int m0   = by * BM;
  const int n0   = bx * BN;
  const int d0   = bz * (D_ / SPLITD);

  const int c0  = wid * 128 + lane;
  const int c1  = c0 + 64;
  const int rA0 = c0 >> 2, cA0 = (c0 & 3) << 3;
  const int rA1 = c1 >> 2, cA1 = (c1 & 3) << 3;
  const u16* aB0 = A + (size_t)(m0 + rA0) * KROW + d0 * IN_ + cA0;
  const u16* aB1 = A + (size_t)(m0 + rA1) * KROW + d0 * IN_ + cA1;
  const u16* bB0 = Wt + ((size_t)d0 * OUT_ + n0 + rA0) * IN_ + cA0;
  const u16* bB1 = Wt + ((size_t)d0 * OUT_ + n0 + rA1) * IN_ + cA1;
  u16* lA0 = As + c0 * 8;
  u16* lA1 = As + c1 * 8;
  u16* lB0 = Bs + c0 * 8;
  u16* lB1 = Bs + c1 * 8;

  const int aOff = (wr * 64 + l16) * BK + quad * 8;
  const int bOff = (wc * 64 + l16) * BK + quad * 8;

  const v4f vzero = {0.f, 0.f, 0.f, 0.f};
  v4f acc[4][4];
#pragma unroll
  for (int mt = 0; mt < 4; ++mt)
#pragma unroll
    for (int nt = 0; nt < 4; ++nt) acc[mt][nt] = vzero;

  for (int dd = 0; dd < D_ / SPLITD; ++dd) {
    const u16* aP0 = aB0 + dd * IN_;
    const u16* aP1 = aB1 + dd * IN_;
    const u16* bP0 = bB0 + (size_t)dd * OUT_ * IN_;
    const u16* bP1 = bB1 + (size_t)dd * OUT_ * IN_;
    for (int it = 0; it < 32; ++it) {
      const int i0 = it * BK;
      gload_lds16(aP0 + i0, lA0);
      gload_lds16(aP1 + i0, lA1);
      gload_lds16(bP0 + i0, lB0);
      gload_lds16(bP1 + i0, lB1);
      __builtin_amdgcn_s_waitcnt(0);
      __syncthreads();

      v8s af[4], bf[4];
#pragma unroll
      for (int mt = 0; mt < 4; ++mt)
        af[mt] = *(const v8s*)(As + aOff + mt * 16 * BK);
#pragma unroll
      for (int nt = 0; nt < 4; ++nt)
        bf[nt] = *(const v8s*)(Bs + bOff + nt * 16 * BK);
#pragma unroll
      for (int mt = 0; mt < 4; ++mt)
#pragma unroll
        for (int nt = 0; nt < 4; ++nt)
          acc[mt][nt] = __builtin_amdgcn_mfma_f32_16x16x32_bf16(
              af[mt], bf[nt], acc[mt][nt], 0, 0, 0);
      __syncthreads();
    }
  }

#pragma unroll
  for (int mt = 0; mt < 4; ++mt) {
#pragma unroll
    for (int r = 0; r < 4; ++r) {
      const int grow = m0 + wr * 64 + mt * 16 + quad * 4 + r;
#pragma unroll
      for (int nt = 0; nt < 4; ++nt) {
        const int col = n0 + wc * 64 + nt * 16 + l16;
        atomicAdd(&out[(size_t)grow * OUT_ + col], acc[mt][nt][r]);
      }
    }
  }
}

// ---- fallback path (R1, proven): used only if ws is too small --------------
__global__ __launch_bounds__(256) void convert_both(
    const float* __restrict__ input, const float* __restrict__ weights,
    u16* __restrict__ inBf, u16* __restrict__ wtBf) {
  int i4 = blockIdx.x * blockDim.x + threadIdx.x;
  const int n4 = (B_ * IN_) / 4;
  const float* src;
  u16* dst;
  int idx;
  if (i4 < n4) { src = input;   dst = inBf; idx = i4; }
  else         { src = weights; dst = wtBf; idx = i4 - n4; }
  float4 v = ((const float4*)src)[idx];
  ushort4 o;
  o.x = f2bf(v.x); o.y = f2bf(v.y); o.z = f2bf(v.z); o.w = f2bf(v.w);
  ((ushort4*)dst)[idx] = o;
}

__global__ __launch_bounds__(256) void gemm_fallback(
    const u16* __restrict__ A, const u16* __restrict__ Wt,
    const float* __restrict__ w, const float* __restrict__ biases,
    float* __restrict__ out) {
  __shared__ __align__(16) u16 As[BM * BK];
  __shared__ __align__(16) u16 Bs[BN * BK];
  const int tid  = threadIdx.x;
  const int wid  = tid >> 6;
  const int lane = tid & 63;
  const int wr   = wid >> 1, wc = wid & 1;
  const int quad = lane >> 4, l16 = lane & 15;
  const int m0   = blockIdx.y * BM;
  const int n0   = blockIdx.x * BN;
  const int c0  = wid * 128 + lane;
  const int c1  = c0 + 64;
  const int rA0 = c0 >> 2, cA0 = (c0 & 3) << 3;
  const int rA1 = c1 >> 2, cA1 = (c1 & 3) << 3;
  const u16* aP0 = A + (size_t)(m0 + rA0) * IN_ + cA0;
  const u16* aP1 = A + (size_t)(m0 + rA1) * IN_ + cA1;
  const u16* bB0 = Wt + (size_t)(n0 + rA0) * IN_ + cA0;
  const u16* bB1 = Wt + (size_t)(n0 + rA1) * IN_ + cA1;
  u16* lA0 = As + c0 * 8;
  u16* lA1 = As + c1 * 8;
  u16* lB0 = Bs + c0 * 8;
  u16* lB1 = Bs + c1 * 8;
  const int aOff = (wr * 64 + l16) * BK + quad * 8;
  const int bOff = (wc * 64 + l16) * BK + quad * 8;
  const v4f vzero = {0.f, 0.f, 0.f, 0.f};
  v4f fin[4][4];
#pragma unroll
  for (int mt = 0; mt < 4; ++mt)
#pragma unroll
    for (int nt = 0; nt < 4; ++nt) fin[mt][nt] = vzero;
  for (int d = 0; d < D_; ++d) {
    const u16* bP0 = bB0 + (size_t)d * OUT_ * IN_;
    const u16* bP1 = bB1 + (size_t)d * OUT_ * IN_;
    v4f acc[4][4];
#pragma unroll
    for (int mt = 0; mt < 4; ++mt)
#pragma unroll
      for (int nt = 0; nt < 4; ++nt) acc[mt][nt] = vzero;
    for (int it = 0; it < 32; ++it) {
      const int i0 = it * BK;
      gload_lds16(aP0 + i0, lA0);
      gload_lds16(aP1 + i0, lA1);
      gload_lds16(bP0 + i0, lB0);
      gload_lds16(bP1 + i0, lB1);
      __builtin_amdgcn_s_waitcnt(0);
      __syncthreads();
      v8s af[4], bf[4];
#pragma unroll
      for (int mt = 0; mt < 4; ++mt)
        af[mt] = *(const v8s*)(As + aOff + mt * 16 * BK);
#pragma unroll
      for (int nt = 0; nt < 4; ++nt)
        bf[nt] = *(const v8s*)(Bs + bOff + nt * 16 * BK);
#pragma unroll
      for (int mt = 0; mt < 4; ++mt)
#pragma unroll
        for (int nt = 0; nt < 4; ++nt)
          acc[mt][nt] = __builtin_amdgcn_mfma_f32_16x16x32_bf16(
              af[mt], bf[nt], acc[mt][nt], 0, 0, 0);
      __syncthreads();
    }
#pragma unroll
    for (int mt = 0; mt < 4; ++mt) {
      const int rowb = m0 + wr * 64 + mt * 16 + quad * 4;
#pragma unroll
      for (int r = 0; r < 4; ++r) {
        const float ws_ = w[(size_t)(rowb + r) * D_ + d];
#pragma unroll
        for (int nt = 0; nt < 4; ++nt) fin[mt][nt][r] += ws_ * acc[mt][nt][r];
      }
    }
  }
  float bcol[4][8];
#pragma unroll
  for (int nt = 0; nt < 4; ++nt) {
    const int col = n0 + wc * 64 + nt * 16 + l16;
#pragma unroll
    for (int dd = 0; dd < 8; ++dd) bcol[nt][dd] = biases[dd * OUT_ + col];
  }
#pragma unroll
  for (int mt = 0; mt < 4; ++mt) {
#pragma unroll
    for (int r = 0; r < 4; ++r) {
      const int grow = m0 + wr * 64 + mt * 16 + quad * 4 + r;
      const v4f* wp = (const v4f*)(w + (size_t)grow * D_);
      const v4f wa = wp[0], wb = wp[1];
#pragma unroll
      for (int nt = 0; nt < 4; ++nt) {
        const int col = n0 + wc * 64 + nt * 16 + l16;
        const float bias = wa[0] * bcol[nt][0] + wa[1] * bcol[nt][1] +
                           wa[2] * bcol[nt][2] + wa[3] * bcol[nt][3] +
                           wb[0] * bcol[nt][4] + wb[1] * bcol[nt][5] +
                           wb[2] * bcol[nt][6] + wb[3] * bcol[nt][7];
        out[(size_t)grow * OUT_ + col] = fin[mt][nt][r] + bias;
      }
    }
  }
}

extern "C" void kernel_launch(void* const* d_in, const int* in_sizes, int n_in,
                              void* d_out, int out_size, void* d_ws, size_t ws_size,
                              hipStream_t stream) {
  const float* input   = (const float*)d_in[0];
  const float* w       = (const float*)d_in[1];
  const float* weights = (const float*)d_in[2];
  const float* biases  = (const float*)d_in[3];
  float* out = (float*)d_out;

  const size_t aS_bytes = (size_t)B_ * KROW * 2;          // 128 MB
  const size_t wt_bytes = (size_t)D_ * OUT_ * IN_ * 2;    // 16 MB

  if (ws_size >= aS_bytes + wt_bytes) {
    u16* aS   = (u16*)d_ws;
    u16* wtBf = (u16*)((char*)d_ws + aS_bytes);
    prep_fused<<<dim3(24576), 256, 0, stream>>>(input, w, weights, biases,
                                                aS, wtBf, out);
    gemm_main<<<dim3(8 * 64 * SPLITD), 256, 0, stream>>>(aS, wtBf, out);
  } else {
    u16* inBf = (u16*)d_ws;
    u16* wtBf = inBf + (size_t)B_ * IN_;
    const int totalF4 = (B_ * IN_ + D_ * OUT_ * IN_) / 4;
    convert_both<<<dim3(totalF4 / 256), 256, 0, stream>>>(input, weights, inBf, wtBf);
    gemm_fallback<<<dim3(OUT_ / BN, B_ / BM), 256, 0, stream>>>(inBf, wtBf, w, biases, out);
  }
}

// Round 5
// 313.471 us; speedup vs baseline: 1.5210x; 1.0749x over previous
//
#include <hip/hip_runtime.h>
#include <stdint.h>

typedef unsigned short u16;
typedef float v4f __attribute__((ext_vector_type(4)));
typedef short v8s __attribute__((ext_vector_type(8)));

#define B_   8192
#define IN_  1024
#define OUT_ 1024
#define D_   8

#define BM 128
#define BN 128
#define BK 32
#define SPLITD 2          // d-range split: 2 halves of 4 epochs (K=4096 each)
#define KROW (D_ * IN_)   // 8192: row length of the scaled-A matrix

__device__ __forceinline__ u16 f2bf(float f) {
  uint32_t u = __float_as_uint(f);
  u += 0x7fffu + ((u >> 16) & 1u);   // round-to-nearest-even (inputs are finite)
  return (u16)(u >> 16);
}

// ---- fused prep ------------------------------------------------------------
//   blocks [0, 8192):      A'[b][d*IN+i] = bf16(w[b,d] * input[b,i])
//   blocks [8192, 16384):  wtBf = bf16(weights)
//   blocks [16384, 24576): out[b,o] = sum_d w[b,d]*biases[d,o]   (R4 path only)
__global__ __launch_bounds__(256) void prep_fused(
    const float* __restrict__ input, const float* __restrict__ w,
    const float* __restrict__ weights, const float* __restrict__ biases,
    u16* __restrict__ aS, u16* __restrict__ wtBf, float* __restrict__ out) {
  const int bid = blockIdx.x;
  const int tid = threadIdx.x;
  if (bid < 8192) {
    const int b  = bid;
    const int i4 = tid;
    float4 v = ((const float4*)(input + (size_t)b * IN_))[i4];
    const float* wr_ = w + (size_t)b * D_;   // wave-uniform -> scalar loads
    ushort4* dst = (ushort4*)aS + (size_t)b * (KROW / 4);
#pragma unroll
    for (int d = 0; d < D_; ++d) {
      const float s = wr_[d];
      ushort4 o;
      o.x = f2bf(s * v.x); o.y = f2bf(s * v.y);
      o.z = f2bf(s * v.z); o.w = f2bf(s * v.w);
      dst[d * (IN_ / 4) + i4] = o;
    }
  } else if (bid < 16384) {
    int idx = (bid - 8192) * 256 + tid;      // one float4 of weights
    float4 v = ((const float4*)weights)[idx];
    ushort4 o;
    o.x = f2bf(v.x); o.y = f2bf(v.y); o.z = f2bf(v.z); o.w = f2bf(v.w);
    ((ushort4*)wtBf)[idx] = o;
  } else {
    int idx = (bid - 16384) * 256 + tid;     // one float4 of out
    int b  = idx >> 8;
    int o4 = (idx & 255) << 2;
    const float* wr_ = w + (size_t)b * D_;
    v4f acc = {0.f, 0.f, 0.f, 0.f};
#pragma unroll
    for (int d = 0; d < D_; ++d) {
      v4f bv = *(const v4f*)(biases + d * OUT_ + o4);
      acc += wr_[d] * bv;
    }
    *(v4f*)(out + (size_t)b * OUT_ + o4) = acc;
  }
}

__device__ __forceinline__ void gload_lds16(const u16* g, u16* l) {
  typedef __attribute__((address_space(1))) void gvoid;
  typedef __attribute__((address_space(3))) void lvoid;
  __builtin_amdgcn_global_load_lds((gvoid*)g, (lvoid*)l, 16, 0, 0);
}

// ---- GEMM core macro-free shared body (m97 structure + XCD swizzle) --------
// Decode: xcd = id & 7 owns y in {xcd, xcd+8, ..., xcd+56}; both z-halves of a
// given y land on the same XCD (FETCH_SIZE 798->136 MB measured in R4).
#define GEMM_PROLOGUE_AND_LOOP                                                \
  __shared__ __align__(16) u16 As[BM * BK];                                   \
  __shared__ __align__(16) u16 Bs[BN * BK];                                   \
  const int id   = blockIdx.x;                                                \
  const int xcd  = id & 7;                                                    \
  const int slot = id >> 3;                                                   \
  const int by   = xcd + ((slot & 7) << 3);                                   \
  const int bx   = (slot >> 3) & 7;                                           \
  const int bz   = slot >> 6;                                                 \
  const int tid  = threadIdx.x;                                               \
  const int wid  = tid >> 6;                                                  \
  const int lane = tid & 63;                                                  \
  const int wr   = wid >> 1, wc = wid & 1;                                    \
  const int quad = lane >> 4, l16 = lane & 15;                                \
  const int m0   = by * BM;                                                   \
  const int n0   = bx * BN;                                                   \
  const int d0   = bz * (D_ / SPLITD);                                        \
  const int c0  = wid * 128 + lane;                                           \
  const int c1  = c0 + 64;                                                    \
  const int rA0 = c0 >> 2, cA0 = (c0 & 3) << 3;                               \
  const int rA1 = c1 >> 2, cA1 = (c1 & 3) << 3;                               \
  const u16* aB0 = A + (size_t)(m0 + rA0) * KROW + d0 * IN_ + cA0;            \
  const u16* aB1 = A + (size_t)(m0 + rA1) * KROW + d0 * IN_ + cA1;            \
  const u16* bB0 = Wt + ((size_t)d0 * OUT_ + n0 + rA0) * IN_ + cA0;           \
  const u16* bB1 = Wt + ((size_t)d0 * OUT_ + n0 + rA1) * IN_ + cA1;           \
  u16* lA0 = As + c0 * 8;                                                     \
  u16* lA1 = As + c1 * 8;                                                     \
  u16* lB0 = Bs + c0 * 8;                                                     \
  u16* lB1 = Bs + c1 * 8;                                                     \
  const int aOff = (wr * 64 + l16) * BK + quad * 8;                           \
  const int bOff = (wc * 64 + l16) * BK + quad * 8;                           \
  const v4f vzero = {0.f, 0.f, 0.f, 0.f};                                     \
  v4f acc[4][4];                                                              \
  _Pragma("unroll")                                                           \
  for (int mt = 0; mt < 4; ++mt)                                              \
    _Pragma("unroll")                                                         \
    for (int nt = 0; nt < 4; ++nt) acc[mt][nt] = vzero;                       \
  for (int dd = 0; dd < D_ / SPLITD; ++dd) {                                  \
    const u16* aP0 = aB0 + dd * IN_;                                          \
    const u16* aP1 = aB1 + dd * IN_;                                          \
    const u16* bP0 = bB0 + (size_t)dd * OUT_ * IN_;                           \
    const u16* bP1 = bB1 + (size_t)dd * OUT_ * IN_;                           \
    for (int it = 0; it < 32; ++it) {                                         \
      const int i0 = it * BK;                                                 \
      gload_lds16(aP0 + i0, lA0);                                             \
      gload_lds16(aP1 + i0, lA1);                                             \
      gload_lds16(bP0 + i0, lB0);                                             \
      gload_lds16(bP1 + i0, lB1);                                             \
      __builtin_amdgcn_s_waitcnt(0);                                          \
      __syncthreads();                                                        \
      v8s af[4], bf[4];                                                       \
      _Pragma("unroll")                                                       \
      for (int mt = 0; mt < 4; ++mt)                                          \
        af[mt] = *(const v8s*)(As + aOff + mt * 16 * BK);                     \
      _Pragma("unroll")                                                       \
      for (int nt = 0; nt < 4; ++nt)                                          \
        bf[nt] = *(const v8s*)(Bs + bOff + nt * 16 * BK);                     \
      _Pragma("unroll")                                                       \
      for (int mt = 0; mt < 4; ++mt)                                          \
        _Pragma("unroll")                                                     \
        for (int nt = 0; nt < 4; ++nt)                                        \
          acc[mt][nt] = __builtin_amdgcn_mfma_f32_16x16x32_bf16(              \
              af[mt], bf[nt], acc[mt][nt], 0, 0, 0);                          \
      __syncthreads();                                                        \
    }                                                                         \
  }

// ---- main-path GEMM: plain stores; z=0 -> out, z=1 -> part -----------------
__global__ __launch_bounds__(256) void gemm_store(
    const u16* __restrict__ A, const u16* __restrict__ Wt,
    float* __restrict__ out, float* __restrict__ part) {
  GEMM_PROLOGUE_AND_LOOP
  float* __restrict__ dst = (bz == 0) ? out : part;
#pragma unroll
  for (int mt = 0; mt < 4; ++mt) {
#pragma unroll
    for (int r = 0; r < 4; ++r) {
      const int grow = m0 + wr * 64 + mt * 16 + quad * 4 + r;
#pragma unroll
      for (int nt = 0; nt < 4; ++nt) {
        const int col = n0 + wc * 64 + nt * 16 + l16;
        dst[(size_t)grow * OUT_ + col] = acc[mt][nt][r];
      }
    }
  }
}

// ---- finale: out = out(z=0 partial) + part(z=1 partial) + sum_d w*biases ---
__global__ __launch_bounds__(256) void finale(
    const float* __restrict__ part, const float* __restrict__ w,
    const float* __restrict__ biases, float* __restrict__ out) {
  const int idx = blockIdx.x * 256 + threadIdx.x;   // one float4 of out
  const int b  = idx >> 8;                          // block-uniform
  const int o4 = (idx & 255) << 2;
  const float* wr_ = w + (size_t)b * D_;
  v4f acc = *(const v4f*)(out + (size_t)b * OUT_ + o4);
  acc += *(const v4f*)(part + (size_t)b * OUT_ + o4);
#pragma unroll
  for (int d = 0; d < D_; ++d) {
    v4f bv = *(const v4f*)(biases + d * OUT_ + o4);
    acc += wr_[d] * bv;
  }
  *(v4f*)(out + (size_t)b * OUT_ + o4) = acc;
}

// ---- R4-path GEMM (atomic epilogue) — fallback if ws too small -------------
__global__ __launch_bounds__(256) void gemm_atomic(
    const u16* __restrict__ A, const u16* __restrict__ Wt,
    float* __restrict__ out) {
  GEMM_PROLOGUE_AND_LOOP
#pragma unroll
  for (int mt = 0; mt < 4; ++mt) {
#pragma unroll
    for (int r = 0; r < 4; ++r) {
      const int grow = m0 + wr * 64 + mt * 16 + quad * 4 + r;
#pragma unroll
      for (int nt = 0; nt < 4; ++nt) {
        const int col = n0 + wc * 64 + nt * 16 + l16;
        atomicAdd(&out[(size_t)grow * OUT_ + col], acc[mt][nt][r]);
      }
    }
  }
}

extern "C" void kernel_launch(void* const* d_in, const int* in_sizes, int n_in,
                              void* d_out, int out_size, void* d_ws, size_t ws_size,
                              hipStream_t stream) {
  const float* input   = (const float*)d_in[0];
  const float* w       = (const float*)d_in[1];
  const float* weights = (const float*)d_in[2];
  const float* biases  = (const float*)d_in[3];
  float* out = (float*)d_out;

  const size_t aS_bytes   = (size_t)B_ * KROW * 2;          // 128 MB
  const size_t wt_bytes   = (size_t)D_ * OUT_ * IN_ * 2;    // 16 MB
  const size_t part_bytes = (size_t)B_ * OUT_ * 4;          // 32 MB

  u16* aS   = (u16*)d_ws;
  u16* wtBf = (u16*)((char*)d_ws + aS_bytes);

  if (ws_size >= aS_bytes + wt_bytes + part_bytes) {
    float* part = (float*)((char*)d_ws + aS_bytes + wt_bytes);
    prep_fused<<<dim3(16384), 256, 0, stream>>>(input, w, weights, biases,
                                                aS, wtBf, out);
    gemm_store<<<dim3(8 * 64 * SPLITD), 256, 0, stream>>>(aS, wtBf, out, part);
    finale<<<dim3(B_ * OUT_ / 4 / 256), 256, 0, stream>>>(part, w, biases, out);
  } else {
    // R4 path: bias pre-write + atomic accumulation
    prep_fused<<<dim3(24576), 256, 0, stream>>>(input, w, weights, biases,
                                                aS, wtBf, out);
    gemm_atomic<<<dim3(8 * 64 * SPLITD), 256, 0, stream>>>(aS, wtBf, out);
  }
}

// Round 6
// 249.782 us; speedup vs baseline: 1.9089x; 1.2550x over previous
//
#include <hip/hip_runtime.h>
#include <stdint.h>

typedef unsigned short u16;
typedef float v4f __attribute__((ext_vector_type(4)));
typedef short v8s __attribute__((ext_vector_type(8)));

#define B_   8192
#define IN_  1024
#define OUT_ 1024
#define D_   8

#define BM 128
#define BN 128
#define BK 64             // K-tile per barrier pair (32 MFMAs amortize the drain)
#define KROW (D_ * IN_)   // 8192: row length of the scaled-A matrix

__device__ __forceinline__ u16 f2bf(float f) {
  uint32_t u = __float_as_uint(f);
  u += 0x7fffu + ((u >> 16) & 1u);   // round-to-nearest-even (inputs are finite)
  return (u16)(u >> 16);
}

// ---- fused prep ------------------------------------------------------------
//   blocks [0, 8192):      A'[b][d*IN+i] = bf16(w[b,d] * input[b,i])
//   blocks [8192, 16384):  wtBf = bf16(weights)
__global__ __launch_bounds__(256) void prep_fused(
    const float* __restrict__ input, const float* __restrict__ w,
    const float* __restrict__ weights,
    u16* __restrict__ aS, u16* __restrict__ wtBf) {
  const int bid = blockIdx.x;
  const int tid = threadIdx.x;
  if (bid < 8192) {
    const int b  = bid;
    const int i4 = tid;
    float4 v = ((const float4*)(input + (size_t)b * IN_))[i4];
    const float* wr_ = w + (size_t)b * D_;   // wave-uniform -> scalar loads
    ushort4* dst = (ushort4*)aS + (size_t)b * (KROW / 4);
#pragma unroll
    for (int d = 0; d < D_; ++d) {
      const float s = wr_[d];
      ushort4 o;
      o.x = f2bf(s * v.x); o.y = f2bf(s * v.y);
      o.z = f2bf(s * v.z); o.w = f2bf(s * v.w);
      dst[d * (IN_ / 4) + i4] = o;
    }
  } else {
    int idx = (bid - 8192) * 256 + tid;      // one float4 of weights
    float4 v = ((const float4*)weights)[idx];
    ushort4 o;
    o.x = f2bf(v.x); o.y = f2bf(v.y); o.z = f2bf(v.z); o.w = f2bf(v.w);
    ((ushort4*)wtBf)[idx] = o;
  }
}

__device__ __forceinline__ void gload_lds16(const u16* g, u16* l) {
  typedef __attribute__((address_space(1))) void gvoid;
  typedef __attribute__((address_space(3))) void lvoid;
  __builtin_amdgcn_global_load_lds((gvoid*)g, (lvoid*)l, 16, 0, 0);
}

// ---- main GEMM -------------------------------------------------------------
// 512 blocks (exactly 2/CU, all resident, no tail), XCD swizzle (id&7 = XCD,
// verified R4: FETCH 798->136 MB). BK=64: 32 MFMAs per barrier pair. K=8192
// per block (full d-range) -> plain stores, bias folded in epilogue.
// LDS is XOR-swizzled: slot column-chunk j' = j ^ (row&7). Swizzle is applied
// on the GLOBAL side of global_load_lds (LDS dest stays lane-contiguous per
// the wave-uniform-base constraint). Reads de-swizzle: chunk (quad+4h)^(l16&7).
// This spreads b128 fragment reads over 8 bank-start groups (optimal phasing);
// unswizzled BK=64 would put all 16 rows on one bank-start (2x LDS time).
__global__ __launch_bounds__(256) void gemm_main(
    const u16* __restrict__ A,        // [B_][KROW] bf16, pre-scaled by w
    const u16* __restrict__ Wt,       // [D_][OUT_][IN_] bf16
    const float* __restrict__ w,      // [B_][D_]
    const float* __restrict__ biases, // [D_][OUT_]
    float* __restrict__ out) {        // [B_][OUT_]
  __shared__ __align__(16) u16 As[BM * BK];   // 16 KB
  __shared__ __align__(16) u16 Bs[BN * BK];   // 16 KB

  const int id   = blockIdx.x;                // 512 blocks
  const int xcd  = id & 7;
  const int slot = id >> 3;                   // 0..63
  const int by   = xcd + ((slot & 7) << 3);   // 0..63, 8 per XCD
  const int bx   = slot >> 3;                 // 0..7

  const int tid  = threadIdx.x;
  const int wid  = tid >> 6;
  const int lane = tid & 63;
  const int wr   = wid >> 1, wc = wid & 1;
  const int quad = lane >> 4, l16 = lane & 15;
  const int m0   = by * BM;
  const int n0   = bx * BN;

  // ---- staging: 1024 chunks of 16B per 16KB tile; thread -> 4 chunks/matrix
  // chunk c = wid*256 + j*64 + lane  (j=0..3); row = c>>3 = wid*32+j*8+(lane>>3)
  // global col chunk is swizzled: swz = (lane&7) ^ ((lane>>3)&7)  (j-invariant)
  const int swz  = (lane & 7) ^ ((lane >> 3) & 7);
  const int rowS = wid * 32 + (lane >> 3);    // + j*8
  const u16* aBase[4];
  const u16* bBase[4];
  u16* lA[4];
  u16* lB[4];
#pragma unroll
  for (int j = 0; j < 4; ++j) {
    const int row = rowS + j * 8;
    aBase[j] = A  + (size_t)(m0 + row) * KROW + swz * 8;
    bBase[j] = Wt + (size_t)(n0 + row) * IN_  + swz * 8;
    const int c = wid * 256 + j * 64 + lane;
    lA[j] = As + c * 8;
    lB[j] = Bs + c * 8;
  }

  // ---- fragment LDS offsets (u16 index), de-swizzled
  const int aRow = wr * 64 + l16;
  const int bRow = wc * 64 + l16;
  const int e    = l16 & 7;
  int aC[2], bC[2];
#pragma unroll
  for (int h = 0; h < 2; ++h) {
    aC[h] = ((quad + 4 * h) ^ e) * 8;
    bC[h] = aC[h];
  }

  const v4f vzero = {0.f, 0.f, 0.f, 0.f};
  v4f acc[4][4];
#pragma unroll
  for (int mt = 0; mt < 4; ++mt)
#pragma unroll
    for (int nt = 0; nt < 4; ++nt) acc[mt][nt] = vzero;

  for (int dd = 0; dd < D_; ++dd) {
    const size_t aOffG = (size_t)dd * IN_;            // k-offset within A row
    const size_t bOffG = (size_t)dd * OUT_ * IN_;     // weights[dd] plane
    for (int it = 0; it < IN_ / BK; ++it) {           // 16 iters
      const int i0 = it * BK;
#pragma unroll
      for (int j = 0; j < 4; ++j) gload_lds16(aBase[j] + aOffG + i0, lA[j]);
#pragma unroll
      for (int j = 0; j < 4; ++j) gload_lds16(bBase[j] + bOffG + i0, lB[j]);
      __builtin_amdgcn_s_waitcnt(0);
      __syncthreads();

#pragma unroll
      for (int h = 0; h < 2; ++h) {
        v8s af[4], bf[4];
#pragma unroll
        for (int mt = 0; mt < 4; ++mt)
          af[mt] = *(const v8s*)(As + (aRow + mt * 16) * BK + aC[h]);
#pragma unroll
        for (int nt = 0; nt < 4; ++nt)
          bf[nt] = *(const v8s*)(Bs + (bRow + nt * 16) * BK + bC[h]);
#pragma unroll
        for (int mt = 0; mt < 4; ++mt)
#pragma unroll
          for (int nt = 0; nt < 4; ++nt)
            acc[mt][nt] = __builtin_amdgcn_mfma_f32_16x16x32_bf16(
                af[mt], bf[nt], acc[mt][nt], 0, 0, 0);
      }
      __syncthreads();
    }
  }

  // ---- epilogue: add bias term sum_d w[b,d]*biases[d,o], plain stores
  float bcol[4][8];
#pragma unroll
  for (int nt = 0; nt < 4; ++nt) {
    const int col = n0 + wc * 64 + nt * 16 + l16;
#pragma unroll
    for (int dd = 0; dd < 8; ++dd) bcol[nt][dd] = biases[dd * OUT_ + col];
  }
#pragma unroll
  for (int mt = 0; mt < 4; ++mt) {
#pragma unroll
    for (int r = 0; r < 4; ++r) {
      const int grow = m0 + wr * 64 + mt * 16 + quad * 4 + r;
      const v4f* wp = (const v4f*)(w + (size_t)grow * D_);
      const v4f wa = wp[0], wb = wp[1];
#pragma unroll
      for (int nt = 0; nt < 4; ++nt) {
        const int col = n0 + wc * 64 + nt * 16 + l16;
        const float bias = wa[0] * bcol[nt][0] + wa[1] * bcol[nt][1] +
                           wa[2] * bcol[nt][2] + wa[3] * bcol[nt][3] +
                           wb[0] * bcol[nt][4] + wb[1] * bcol[nt][5] +
                           wb[2] * bcol[nt][6] + wb[3] * bcol[nt][7];
        out[(size_t)grow * OUT_ + col] = acc[mt][nt][r] + bias;
      }
    }
  }
}

// ---- fallback path (R1, proven): used only if ws is too small --------------
#define FBK 32
__global__ __launch_bounds__(256) void convert_both(
    const float* __restrict__ input, const float* __restrict__ weights,
    u16* __restrict__ inBf, u16* __restrict__ wtBf) {
  int i4 = blockIdx.x * blockDim.x + threadIdx.x;
  const int n4 = (B_ * IN_) / 4;
  const float* src;
  u16* dst;
  int idx;
  if (i4 < n4) { src = input;   dst = inBf; idx = i4; }
  else         { src = weights; dst = wtBf; idx = i4 - n4; }
  float4 v = ((const float4*)src)[idx];
  ushort4 o;
  o.x = f2bf(v.x); o.y = f2bf(v.y); o.z = f2bf(v.z); o.w = f2bf(v.w);
  ((ushort4*)dst)[idx] = o;
}

__global__ __launch_bounds__(256) void gemm_fallback(
    const u16* __restrict__ A, const u16* __restrict__ Wt,
    const float* __restrict__ w, const float* __restrict__ biases,
    float* __restrict__ out) {
  __shared__ __align__(16) u16 As[BM * FBK];
  __shared__ __align__(16) u16 Bs[BN * FBK];
  const int tid  = threadIdx.x;
  const int wid  = tid >> 6;
  const int lane = tid & 63;
  const int wr   = wid >> 1, wc = wid & 1;
  const int quad = lane >> 4, l16 = lane & 15;
  const int m0   = blockIdx.y * BM;
  const int n0   = blockIdx.x * BN;
  const int c0  = wid * 128 + lane;
  const int c1  = c0 + 64;
  const int rA0 = c0 >> 2, cA0 = (c0 & 3) << 3;
  const int rA1 = c1 >> 2, cA1 = (c1 & 3) << 3;
  const u16* aP0 = A + (size_t)(m0 + rA0) * IN_ + cA0;
  const u16* aP1 = A + (size_t)(m0 + rA1) * IN_ + cA1;
  const u16* bB0 = Wt + (size_t)(n0 + rA0) * IN_ + cA0;
  const u16* bB1 = Wt + (size_t)(n0 + rA1) * IN_ + cA1;
  u16* lA0 = As + c0 * 8;
  u16* lA1 = As + c1 * 8;
  u16* lB0 = Bs + c0 * 8;
  u16* lB1 = Bs + c1 * 8;
  const int aOff = (wr * 64 + l16) * FBK + quad * 8;
  const int bOff = (wc * 64 + l16) * FBK + quad * 8;
  const v4f vzero = {0.f, 0.f, 0.f, 0.f};
  v4f fin[4][4];
#pragma unroll
  for (int mt = 0; mt < 4; ++mt)
#pragma unroll
    for (int nt = 0; nt < 4; ++nt) fin[mt][nt] = vzero;
  for (int d = 0; d < D_; ++d) {
    const u16* bP0 = bB0 + (size_t)d * OUT_ * IN_;
    const u16* bP1 = bB1 + (size_t)d * OUT_ * IN_;
    v4f acc[4][4];
#pragma unroll
    for (int mt = 0; mt < 4; ++mt)
#pragma unroll
      for (int nt = 0; nt < 4; ++nt) acc[mt][nt] = vzero;
    for (int it = 0; it < 32; ++it) {
      const int i0 = it * FBK;
      gload_lds16(aP0 + i0, lA0);
      gload_lds16(aP1 + i0, lA1);
      gload_lds16(bP0 + i0, lB0);
      gload_lds16(bP1 + i0, lB1);
      __builtin_amdgcn_s_waitcnt(0);
      __syncthreads();
      v8s af[4], bf[4];
#pragma unroll
      for (int mt = 0; mt < 4; ++mt)
        af[mt] = *(const v8s*)(As + aOff + mt * 16 * FBK);
#pragma unroll
      for (int nt = 0; nt < 4; ++nt)
        bf[nt] = *(const v8s*)(Bs + bOff + nt * 16 * FBK);
#pragma unroll
      for (int mt = 0; mt < 4; ++mt)
#pragma unroll
        for (int nt = 0; nt < 4; ++nt)
          acc[mt][nt] = __builtin_amdgcn_mfma_f32_16x16x32_bf16(
              af[mt], bf[nt], acc[mt][nt], 0, 0, 0);
      __syncthreads();
    }
#pragma unroll
    for (int mt = 0; mt < 4; ++mt) {
      const int rowb = m0 + wr * 64 + mt * 16 + quad * 4;
#pragma unroll
      for (int r = 0; r < 4; ++r) {
        const float ws_ = w[(size_t)(rowb + r) * D_ + d];
#pragma unroll
        for (int nt = 0; nt < 4; ++nt) fin[mt][nt][r] += ws_ * acc[mt][nt][r];
      }
    }
  }
  float bcol[4][8];
#pragma unroll
  for (int nt = 0; nt < 4; ++nt) {
    const int col = n0 + wc * 64 + nt * 16 + l16;
#pragma unroll
    for (int dd = 0; dd < 8; ++dd) bcol[nt][dd] = biases[dd * OUT_ + col];
  }
#pragma unroll
  for (int mt = 0; mt < 4; ++mt) {
#pragma unroll
    for (int r = 0; r < 4; ++r) {
      const int grow = m0 + wr * 64 + mt * 16 + quad * 4 + r;
      const v4f* wp = (const v4f*)(w + (size_t)grow * D_);
      const v4f wa = wp[0], wb = wp[1];
#pragma unroll
      for (int nt = 0; nt < 4; ++nt) {
        const int col = n0 + wc * 64 + nt * 16 + l16;
        const float bias = wa[0] * bcol[nt][0] + wa[1] * bcol[nt][1] +
                           wa[2] * bcol[nt][2] + wa[3] * bcol[nt][3] +
                           wb[0] * bcol[nt][4] + wb[1] * bcol[nt][5] +
                           wb[2] * bcol[nt][6] + wb[3] * bcol[nt][7];
        out[(size_t)grow * OUT_ + col] = fin[mt][nt][r] + bias;
      }
    }
  }
}

extern "C" void kernel_launch(void* const* d_in, const int* in_sizes, int n_in,
                              void* d_out, int out_size, void* d_ws, size_t ws_size,
                              hipStream_t stream) {
  const float* input   = (const float*)d_in[0];
  const float* w       = (const float*)d_in[1];
  const float* weights = (const float*)d_in[2];
  const float* biases  = (const float*)d_in[3];
  float* out = (float*)d_out;

  const size_t aS_bytes = (size_t)B_ * KROW * 2;          // 128 MB
  const size_t wt_bytes = (size_t)D_ * OUT_ * IN_ * 2;    // 16 MB

  if (ws_size >= aS_bytes + wt_bytes) {
    u16* aS   = (u16*)d_ws;
    u16* wtBf = (u16*)((char*)d_ws + aS_bytes);
    prep_fused<<<dim3(16384), 256, 0, stream>>>(input, w, weights, aS, wtBf);
    gemm_main<<<dim3(512), 256, 0, stream>>>(aS, wtBf, w, biases, out);
  } else {
    u16* inBf = (u16*)d_ws;
    u16* wtBf = inBf + (size_t)B_ * IN_;
    const int totalF4 = (B_ * IN_ + D_ * OUT_ * IN_) / 4;
    convert_both<<<dim3(totalF4 / 256), 256, 0, stream>>>(input, weights, inBf, wtBf);
    gemm_fallback<<<dim3(OUT_ / BN, B_ / BM), 256, 0, stream>>>(inBf, wtBf, w, biases, out);
  }
}